// Round 10
// baseline (143.003 us; speedup 1.0000x reference)
//
#include <hip/hip_runtime.h>
#include <hip/hip_bf16.h>

// GAT layer: h = doc@W + Wb; s1 = h@a1, s2 = h@a2;
// score[i,j] = lrelu(s1[i]+s2[j]+ab); att = softmax_rows(score); out = lrelu(att@h)
// N=8192, IN=512, D=256. Outputs: out (8192*256) then att (8192*8192), fp32.
//
// exp(lrelu(s1a+s2j)) = (s2j >= -s1a) ? exp(s1a)*e2[j] : exp(.1*s1a)*e02[j]
// -> no transcendentals in N^2 loops.
// h via bf16-split MFMA: x = hi+lo; hi*hi + hi*lo + lo*hi ~ fp32 (2^-17 rel).
// att stores batched 8 windows (1 KB per row) -> HBM page-hit bursts.

typedef __attribute__((ext_vector_type(4))) float f32x4;
typedef __attribute__((ext_vector_type(8))) short short8;
typedef __attribute__((ext_vector_type(4))) unsigned short ushort4v;

#define SLOPE 0.1f
#define NROW 8192
#define DDIM 256

__device__ __forceinline__ float lrelu(float x){ return fmaxf(x, SLOPE * x); }

__device__ __forceinline__ unsigned short f2bf(float f){
  union { float f; unsigned u; } v; v.f = f;
  unsigned r = (v.u + 0x7fffu + ((v.u >> 16) & 1u)) >> 16;
  return (unsigned short)r;
}
__device__ __forceinline__ float bf2f(unsigned short u){
  union { unsigned u; float f; } v; v.u = (unsigned)u << 16; return v.f;
}
__device__ __forceinline__ unsigned cvt_pk_bf16(float lo, float hi){
  unsigned r;
  asm("v_cvt_pk_bf16_f32 %0, %1, %2" : "=v"(r) : "v"(lo), "v"(hi));
  return r;
}

// ---------------- K0: Wt_hi/Wt_lo [256][512] bf16 split-transpose of W ----------------
__global__ __launch_bounds__(256) void k_prep(
    const float* __restrict__ W,
    unsigned short* __restrict__ Wt_hi, unsigned short* __restrict__ Wt_lo)
{
  const int tid = blockIdx.x * 256 + threadIdx.x;   // 32768 total
  const int c = tid >> 7, kq = tid & 127;
  ushort4v hi, lo;
#pragma unroll
  for (int j = 0; j < 4; ++j) {
    const float v = W[(size_t)(kq * 4 + j) * 256 + c];
    hi[j] = f2bf(v);
    lo[j] = f2bf(v - bf2f(hi[j]));
  }
  *reinterpret_cast<ushort4v*>(Wt_hi + (size_t)c * 512 + kq * 4) = hi;
  *reinterpret_cast<ushort4v*>(Wt_lo + (size_t)c * 512 + kq * 4) = lo;
}

// ---------------- K1: h-tile via split MFMA; fused s1/s2/e2/e02 + ht bf16 ----------------
// 512 threads = 8 waves. Block = 32 rows x 256 cols; wave w owns cols w*32..+31.
__global__ __launch_bounds__(512, 2) void k_h(
    const float* __restrict__ doc, const unsigned short* __restrict__ Wt_hi,
    const unsigned short* __restrict__ Wt_lo, const float* __restrict__ Wb,
    const float* __restrict__ a,
    unsigned short* __restrict__ ht, float* __restrict__ s1,
    float* __restrict__ e2, float* __restrict__ e02)
{
  __shared__ __align__(16) short8 aH[2][2][64];   // [buf][rt][lane] 4 KB
  __shared__ __align__(16) short8 aL[2][2][64];   // 4 KB
  __shared__ float sred[8][2][32];                // 2 KB

  const int t = threadIdx.x, w = t >> 6, l = t & 63;
  const int lr = l & 15, lg = l >> 4;
  const int rb = blockIdx.x * 32;
  const int cb = w * 32;

  f32x4 acc[2][2];
#pragma unroll
  for (int rt = 0; rt < 2; ++rt)
#pragma unroll
    for (int ct = 0; ct < 2; ++ct) acc[rt][ct] = (f32x4){0.f, 0.f, 0.f, 0.f};

  const float* docp = doc + (size_t)(rb + w * 16 + lr) * 512 + lg * 8;  // valid for w<2

  f32x4 v0, v1;
  auto loadDoc = [&](int k0) { if (w < 2) {
      v0 = *reinterpret_cast<const f32x4*>(docp + k0);
      v1 = *reinterpret_cast<const f32x4*>(docp + k0 + 4);
  }};
  auto writeStage = [&](int pb) { if (w < 2) {
      union { short8 v; unsigned short u[8]; } hi, lo;
#pragma unroll
      for (int q = 0; q < 4; ++q) {
        hi.u[q] = f2bf(v0[q]);     lo.u[q] = f2bf(v0[q] - bf2f(hi.u[q]));
        hi.u[4+q] = f2bf(v1[q]);   lo.u[4+q] = f2bf(v1[q] - bf2f(hi.u[4+q]));
      }
      aH[pb][w][l] = hi.v;
      aL[pb][w][l] = lo.v;
  }};

  loadDoc(0); writeStage(0); loadDoc(32);

  for (int n = 0; n < 16; ++n) {
    const int kk = n * 32;
    const int par = n & 1;

    asm volatile("s_waitcnt lgkmcnt(0)\n\ts_barrier" ::: "memory");

    const short8 ah0 = aH[par][0][l];
    const short8 ah1 = aH[par][1][l];
    const short8 al0 = aL[par][0][l];
    const short8 al1 = aL[par][1][l];

    short8 bh[2], bl[2];
#pragma unroll
    for (int ct = 0; ct < 2; ++ct) {
      const size_t off = (size_t)(cb + ct * 16 + lr) * 512 + kk + lg * 8;
      bh[ct] = *reinterpret_cast<const short8*>(Wt_hi + off);
      bl[ct] = *reinterpret_cast<const short8*>(Wt_lo + off);
    }

    if (n + 1 < 16) writeStage(par ^ 1);
    if (n + 2 < 16) loadDoc((n + 2) * 32);

#pragma unroll
    for (int ct = 0; ct < 2; ++ct) {
      acc[0][ct] = __builtin_amdgcn_mfma_f32_16x16x32_bf16(ah0, bh[ct], acc[0][ct], 0, 0, 0);
      acc[1][ct] = __builtin_amdgcn_mfma_f32_16x16x32_bf16(ah1, bh[ct], acc[1][ct], 0, 0, 0);
      acc[0][ct] = __builtin_amdgcn_mfma_f32_16x16x32_bf16(ah0, bl[ct], acc[0][ct], 0, 0, 0);
      acc[1][ct] = __builtin_amdgcn_mfma_f32_16x16x32_bf16(ah1, bl[ct], acc[1][ct], 0, 0, 0);
      acc[0][ct] = __builtin_amdgcn_mfma_f32_16x16x32_bf16(al0, bh[ct], acc[0][ct], 0, 0, 0);
      acc[1][ct] = __builtin_amdgcn_mfma_f32_16x16x32_bf16(al1, bh[ct], acc[1][ct], 0, 0, 0);
    }
  }

  float bias[2];
#pragma unroll
  for (int ct = 0; ct < 2; ++ct) bias[ct] = Wb[cb + ct * 16 + lr];
#pragma unroll
  for (int rt = 0; rt < 2; ++rt)
#pragma unroll
    for (int ct = 0; ct < 2; ++ct) {
#pragma unroll
      for (int q = 0; q < 4; ++q) acc[rt][ct][q] += bias[ct];
      ushort4v u;
#pragma unroll
      for (int q = 0; q < 4; ++q) u[q] = f2bf(acc[rt][ct][q]);
      *reinterpret_cast<ushort4v*>(
          ht + (size_t)(cb + ct * 16 + lr) * 8192 + rb + rt * 16 + lg * 4) = u;
    }

  // s1/s2 over this wave's 32 cols; reduce over lr then waves
  float a1c[2], a2c[2];
#pragma unroll
  for (int ct = 0; ct < 2; ++ct) {
    a1c[ct] = a[cb + ct * 16 + lr];
    a2c[ct] = a[256 + cb + ct * 16 + lr];
  }
  float p1[2][4], p2[2][4];
#pragma unroll
  for (int rt = 0; rt < 2; ++rt)
#pragma unroll
    for (int q = 0; q < 4; ++q) {
      float x1 = 0.f, x2 = 0.f;
#pragma unroll
      for (int ct = 0; ct < 2; ++ct) {
        x1 = fmaf(acc[rt][ct][q], a1c[ct], x1);
        x2 = fmaf(acc[rt][ct][q], a2c[ct], x2);
      }
#pragma unroll
      for (int off = 1; off < 16; off <<= 1) {
        x1 += __shfl_xor(x1, off);
        x2 += __shfl_xor(x2, off);
      }
      p1[rt][q] = x1; p2[rt][q] = x2;
    }
  __syncthreads();
  if (lr == 0) {
#pragma unroll
    for (int rt = 0; rt < 2; ++rt)
#pragma unroll
      for (int q = 0; q < 4; ++q) {
        sred[w][0][rt * 16 + lg * 4 + q] = p1[rt][q];
        sred[w][1][rt * 16 + lg * 4 + q] = p2[rt][q];
      }
  }
  __syncthreads();
  if (t < 32) {
    float v1s = 0.f, v2s = 0.f;
#pragma unroll
    for (int ww = 0; ww < 8; ++ww) { v1s += sred[ww][0][t]; v2s += sred[ww][1][t]; }
    const int r = rb + t;
    s1[r] = v1s;
    e2[r] = __expf(v2s);
    e02[r] = __expf(SLOPE * v2s);
  }
}

// ---------------- K3: per-row Z -> rowinfo {E1*iz, E01*iz, T, iz} ----------------
__global__ __launch_bounds__(256) void k_z(
    const float* __restrict__ s1, const float* __restrict__ e2g,
    const float* __restrict__ e02g, const float* __restrict__ abp,
    float* __restrict__ rowinfo)
{
  __shared__ __align__(16) float es[8192];
  __shared__ __align__(16) float fs[8192];
  const int t = threadIdx.x;
  for (int i = t * 4; i < 8192; i += 1024) {
    *reinterpret_cast<f32x4*>(&es[i]) = *reinterpret_cast<const f32x4*>(e2g + i);
    *reinterpret_cast<f32x4*>(&fs[i]) = *reinterpret_cast<const f32x4*>(e02g + i);
  }
  __syncthreads();
  const int w = t >> 6, l = t & 63;
  const float ab = abp[0];
  const int rb = blockIdx.x * 16 + w * 4;
  float T[4], E1[4], E01[4];
#pragma unroll
  for (int rr = 0; rr < 4; ++rr) {
    const float s1a = s1[rb + rr] + ab;
    E1[rr] = __expf(s1a); E01[rr] = __expf(SLOPE * s1a); T[rr] = __expf(-s1a);
  }
  float zA[4] = {0.f,0.f,0.f,0.f}, zB[4] = {0.f,0.f,0.f,0.f};
  for (int i = l * 4; i < 8192; i += 256) {
    const f32x4 e = *reinterpret_cast<const f32x4*>(&es[i]);
    const f32x4 f = *reinterpret_cast<const f32x4*>(&fs[i]);
#pragma unroll
    for (int rr = 0; rr < 4; ++rr)
#pragma unroll
      for (int q = 0; q < 4; ++q) {
        const bool c = (e[q] >= T[rr]);
        zA[rr] += c ? e[q] : 0.f;
        zB[rr] += c ? 0.f : f[q];
      }
  }
#pragma unroll
  for (int rr = 0; rr < 4; ++rr) {
    float z = E1[rr] * zA[rr] + E01[rr] * zB[rr];
#pragma unroll
    for (int off = 32; off > 0; off >>= 1) z += __shfl_down(z, off);
    if (l == 0) {
      const float iz = 1.0f / z;
      f32x4 ri = (f32x4){E1[rr] * iz, E01[rr] * iz, T[rr], iz};
      *reinterpret_cast<f32x4*>(rowinfo + (size_t)(rb + rr) * 4) = ri;
    }
  }
}

// ---------------- K4: att + partial out via MFMA, split-K, batched stores ----------------
// grid (KS, 128), block 512 = 8 waves. 64 rows/block, 32-k windows in batches of 8.
// Wave w: cols w*32..+31; generates p for rows rb+w*8..+7.
// p kept in pq[0..7] regs (static idx, unrolled batch); 8 nt-stores flushed
// back-to-back per batch -> each row gets a contiguous 1 KB burst (HBM page hits),
// and stores are temporally decoupled from all b-load vmcnt waits.
__global__ __launch_bounds__(512, 3) void k_att(
    const float* __restrict__ rowinfo, const float* __restrict__ e2g,
    const float* __restrict__ e02g, const unsigned short* __restrict__ ht,
    float* __restrict__ att, float* __restrict__ part, int CHUNK)
{
  extern __shared__ __align__(16) char smem[];
  char* plsb  = smem;                                    // [2][4][64] short8 = 8 KB
  float* e2s  = reinterpret_cast<float*>(smem + 8192);   // CHUNK
  float* e02s = e2s + CHUNK;                             // CHUNK

  const int t = threadIdx.x, w = t >> 6, l = t & 63;
  const int lr = l & 15, lg = l >> 4;
  const int kbase = blockIdx.x * CHUNK;     // slice (fastest -> XCD)
  const int rb = blockIdx.y * 64;

  for (int i = t * 4; i < CHUNK; i += 2048) {
    *reinterpret_cast<f32x4*>(e2s + i)  = *reinterpret_cast<const f32x4*>(e2g + kbase + i);
    *reinterpret_cast<f32x4*>(e02s + i) = *reinterpret_cast<const f32x4*>(e02g + kbase + i);
  }

  // ---- writer role: 8 rows per wave ----
  const int r = l >> 3, jc = l & 7;
  const int rowW = rb + w * 8 + r;
  const f32x4 ri = *reinterpret_cast<const f32x4*>(rowinfo + (size_t)rowW * 4);
  const float E1z = ri[0], E01z = ri[1], T = ri[2];
  float* attW = att + (size_t)rowW * 8192 + kbase + jc * 4;
  const int fragoff = (w >> 1) * 1024 + ((jc >> 1) * 16 + (w & 1) * 8 + r) * 16 + (jc & 1) * 8;

  __syncthreads();

  f32x4 pq[8];   // att p-values for the current batch (STATIC indices only)

#define GEN(kw, pb, slot) { \
    const f32x4 eA_ = *reinterpret_cast<const f32x4*>(e2s + (kw) + jc * 4); \
    const f32x4 fA_ = *reinterpret_cast<const f32x4*>(e02s + (kw) + jc * 4); \
    f32x4 pA_; \
    _Pragma("unroll") \
    for (int q = 0; q < 4; ++q) { \
      const bool cA_ = (eA_[q] >= T); \
      pA_[q] = (cA_ ? E1z : E01z) * (cA_ ? eA_[q] : fA_[q]); \
    } \
    pq[slot] = pA_; \
    uint2 uu_; \
    uu_.x = cvt_pk_bf16(pA_[0], pA_[1]); uu_.y = cvt_pk_bf16(pA_[2], pA_[3]); \
    *reinterpret_cast<uint2*>(plsb + (pb) * 4096 + fragoff) = uu_; \
  }

#define FLUSH(bk) { \
    float* fb_ = attW + (bk); \
    __builtin_nontemporal_store(pq[0], reinterpret_cast<f32x4*>(fb_)); \
    __builtin_nontemporal_store(pq[1], reinterpret_cast<f32x4*>(fb_ + 32)); \
    __builtin_nontemporal_store(pq[2], reinterpret_cast<f32x4*>(fb_ + 64)); \
    __builtin_nontemporal_store(pq[3], reinterpret_cast<f32x4*>(fb_ + 96)); \
    __builtin_nontemporal_store(pq[4], reinterpret_cast<f32x4*>(fb_ + 128)); \
    __builtin_nontemporal_store(pq[5], reinterpret_cast<f32x4*>(fb_ + 160)); \
    __builtin_nontemporal_store(pq[6], reinterpret_cast<f32x4*>(fb_ + 192)); \
    __builtin_nontemporal_store(pq[7], reinterpret_cast<f32x4*>(fb_ + 224)); \
  }

  const unsigned short* hbase = ht + (size_t)(w * 32 + lr) * 8192 + kbase + lg * 8;
  auto loadB = [&](short8* b, int n) {
    const int kk = n * 32;
    b[0] = *reinterpret_cast<const short8*>(hbase + kk);
    b[1] = *reinterpret_cast<const short8*>(hbase + kk + (size_t)16 * 8192);
  };

  f32x4 acc[4][2];
#pragma unroll
  for (int rt = 0; rt < 4; ++rt)
#pragma unroll
    for (int ct = 0; ct < 2; ++ct) acc[rt][ct] = (f32x4){0.f, 0.f, 0.f, 0.f};

  auto mma = [&](const short8* b, const short8& af0, const short8& af1,
                 const short8& af2, const short8& af3) {
    __builtin_amdgcn_s_setprio(1);
    acc[0][0] = __builtin_amdgcn_mfma_f32_16x16x32_bf16(af0, b[0], acc[0][0], 0, 0, 0);
    acc[1][0] = __builtin_amdgcn_mfma_f32_16x16x32_bf16(af1, b[0], acc[1][0], 0, 0, 0);
    acc[2][0] = __builtin_amdgcn_mfma_f32_16x16x32_bf16(af2, b[0], acc[2][0], 0, 0, 0);
    acc[3][0] = __builtin_amdgcn_mfma_f32_16x16x32_bf16(af3, b[0], acc[3][0], 0, 0, 0);
    acc[0][1] = __builtin_amdgcn_mfma_f32_16x16x32_bf16(af0, b[1], acc[0][1], 0, 0, 0);
    acc[1][1] = __builtin_amdgcn_mfma_f32_16x16x32_bf16(af1, b[1], acc[1][1], 0, 0, 0);
    acc[2][1] = __builtin_amdgcn_mfma_f32_16x16x32_bf16(af2, b[1], acc[2][1], 0, 0, 0);
    acc[3][1] = __builtin_amdgcn_mfma_f32_16x16x32_bf16(af3, b[1], acc[3][1], 0, 0, 0);
    __builtin_amdgcn_s_setprio(0);
  };

  short8 bAr[2], bBr[2];
  loadB(bAr, 0);          // b(0) issued first
  GEN(0, 0, 0);           // window 0 -> buf0, slot 0

  const int NIT = CHUNK / 32;     // 64/128/256 (divisible by 8)
  const int NB = NIT / 8;
  const short8* buf0 = reinterpret_cast<const short8*>(plsb);
  const short8* buf1 = reinterpret_cast<const short8*>(plsb + 4096);

  for (int b = 0; b < NB; ++b) {
    const int kb2 = b * 256;      // batch k-origin
#pragma unroll
    for (int u = 0; u < 8; u += 2) {
      const int kk = kb2 + u * 32;
      // even window m = b*8+u : frags buf0, b regs bAr
      loadB(bBr, b * 8 + u + 1);  // m+1 <= b*8+7 < NIT always
      asm volatile("s_waitcnt lgkmcnt(0)\n\ts_barrier" ::: "memory");
      {
        const short8 af0 = buf0[0 * 64 + l];
        const short8 af1 = buf0[1 * 64 + l];
        const short8 af2 = buf0[2 * 64 + l];
        const short8 af3 = buf0[3 * 64 + l];
        GEN(kk + 32, 1, ((u + 1) & 7));        // gen window m+1 (odd -> buf1)
        if (u == 6) FLUSH(kb2);                // batch complete: 1 KB/row burst
        mma(bAr, af0, af1, af2, af3);
      }
      // odd window m+1 : frags buf1, b regs bBr
      const int m2 = b * 8 + u + 2;
      if (m2 < NIT) loadB(bAr, m2);
      asm volatile("s_waitcnt lgkmcnt(0)\n\ts_barrier" ::: "memory");
      {
        const short8 af0 = buf1[0 * 64 + l];
        const short8 af1 = buf1[1 * 64 + l];
        const short8 af2 = buf1[2 * 64 + l];
        const short8 af3 = buf1[3 * 64 + l];
        if (m2 < NIT) GEN(kb2 + (u + 2) * 32, 0, ((u + 2) & 7));  // next (even -> buf0)
        mma(bBr, af0, af1, af2, af3);
      }
    }
  }
#undef GEN
#undef FLUSH

  float* pb = part + (size_t)blockIdx.x * ((size_t)NROW * DDIM);
#pragma unroll
  for (int rt = 0; rt < 4; ++rt)
#pragma unroll
    for (int ct = 0; ct < 2; ++ct)
#pragma unroll
      for (int q = 0; q < 4; ++q)
        __builtin_nontemporal_store(acc[rt][ct][q],
            pb + (size_t)(rb + rt * 16 + lg * 4 + q) * 256 + w * 32 + ct * 16 + lr);
}

// ---------------- K5: out = lrelu(sum_k part[k]) ----------------
__global__ __launch_bounds__(256) void k_reduce(
    const float* __restrict__ part, float* __restrict__ out, int KS)
{
  const size_t idx = ((size_t)blockIdx.x * 256 + threadIdx.x) * 4;
  f32x4 s = __builtin_nontemporal_load(reinterpret_cast<const f32x4*>(part + idx));
  for (int k = 1; k < KS; ++k) {
    const f32x4 v = __builtin_nontemporal_load(
        reinterpret_cast<const f32x4*>(part + (size_t)k * NROW * DDIM + idx));
#pragma unroll
    for (int q = 0; q < 4; ++q) s[q] += v[q];
  }
#pragma unroll
  for (int q = 0; q < 4; ++q) s[q] = lrelu(s[q]);
  __builtin_nontemporal_store(s, reinterpret_cast<f32x4*>(out + idx));
}

extern "C" void kernel_launch(void* const* d_in, const int* in_sizes, int n_in,
                              void* d_out, int out_size, void* d_ws, size_t ws_size,
                              hipStream_t stream)
{
  const float* doc = (const float*)d_in[0];
  const float* W   = (const float*)d_in[1];
  const float* Wb  = (const float*)d_in[2];
  const float* a   = (const float*)d_in[3];
  const float* ab  = (const float*)d_in[4];

  float* out = (float*)d_out;                 // 8192*256
  float* att = out + (size_t)8192 * 256;      // 8192*8192

  char* ws = (char*)d_ws;
  unsigned short* ht    = (unsigned short*)ws;                              // 4 MB
  unsigned short* Wt_hi = (unsigned short*)(ws + (size_t)4 * 1024 * 1024);  // 256 KB
  unsigned short* Wt_lo = Wt_hi + (size_t)256 * 512;                        // 256 KB
  float* s1      = (float*)(ws + (size_t)4 * 1024 * 1024 + 512 * 1024);     // 32 KB
  float* e2      = s1 + 8192;
  float* e02     = e2 + 8192;
  float* rowinfo = e02 + 8192;                                              // 128 KB
  const size_t base = (size_t)5 * 1024 * 1024;
  const size_t partBytes = (size_t)NROW * DDIM * sizeof(float);             // 8 MB

  int KS = 1;
  for (int c = 4; c >= 1; c >>= 1)
    if (base + (size_t)c * partBytes <= ws_size) { KS = c; break; }
  float* part = (float*)(ws + base);
  const int CHUNK = NROW / KS;
  const size_t smem = 8192 + (size_t)2 * CHUNK * sizeof(float);

  hipLaunchKernelGGL(k_prep,   dim3(128),     dim3(256), 0,    stream, W, Wt_hi, Wt_lo);
  hipLaunchKernelGGL(k_h,      dim3(256),     dim3(512), 0,    stream, doc, Wt_hi, Wt_lo, Wb, a, ht, s1, e2, e02);
  hipLaunchKernelGGL(k_z,      dim3(512),     dim3(256), 0,    stream, s1, e2, e02, ab, rowinfo);
  hipLaunchKernelGGL(k_att,    dim3(KS, 128), dim3(512), smem, stream, rowinfo, e2, e02, ht, att, part, CHUNK);
  hipLaunchKernelGGL(k_reduce, dim3(2048),    dim3(256), 0,    stream, part, out, KS);
}